// Round 13
// baseline (115.101 us; speedup 1.0000x reference)
//
#include <hip/hip_runtime.h>

#define BB     4
#define T_IN   12
#define T_OUT  24
#define NNODES 5000
#define CC     32
#define HH     8
#define K1     17
#define O_OUT  12
#define XSTRIDE (NNODES*CC)   // floats per (b,t) plane
#define TPU     (NNODES*16)   // dwords per (b,t) plane in bf16 mirror [b][t][n][c2]

// V j-pair-packed: Vb2[n][q(4)][jp(9)][t(3)][o(12)] dwords;
// dword = (bf16 V[2jp,t,o] low, bf16 V[2jp+1,t,o] high); jp=8 high half = 0.
#define JP      9
#define VJPD    36                // dwords per (q,jp) block = 3*12
#define VQD     (JP*VJPD)         // 324 dwords per (n,q)
#define VND     (4*VQD)           // 1296 dwords per node

// ---------------- kernel: global max (fallback path only) ----------------
__global__ void max_reduce_kernel(const float* __restrict__ d, int n,
                                  unsigned* __restrict__ out) {
    float m = 0.0f;
    for (int i = blockIdx.x * blockDim.x + threadIdx.x; i < n;
         i += gridDim.x * blockDim.x)
        m = fmaxf(m, d[i]);
#pragma unroll
    for (int off = 32; off > 0; off >>= 1)
        m = fmaxf(m, __shfl_down(m, off, 64));
    if ((threadIdx.x & 63) == 0)
        atomicMax(out, __float_as_uint(m));
}

__device__ inline unsigned bf16rne(float f) {
    unsigned u = __float_as_uint(f);
    return (u + 0x7FFFu + ((u >> 16) & 1u)) >> 16;
}

// --- prep5b: fused max-reduce + copy x->out[:, :T_IN] + coalesced mirror ---
// mirror layout [b][t][n][c2]: consecutive threads write consecutive uint2.
__global__ void prep5b_kernel(const float4* __restrict__ x,
                              float4* __restrict__ out,
                              uint2* __restrict__ xbu,
                              const float* __restrict__ nd,
                              unsigned* __restrict__ maxbits) {
    const int gs = gridDim.x * blockDim.x;
    const int g0 = blockIdx.x * blockDim.x + threadIdx.x;

    // ---- part 0: global max over nearest_dists (vbuild4 reads it later) ----
    {
        float m = 0.0f;  // dists >= 0
        for (int i = g0; i < NNODES * K1; i += gs) m = fmaxf(m, nd[i]);
#pragma unroll
        for (int off = 32; off > 0; off >>= 1)
            m = fmaxf(m, __shfl_down(m, off, 64));
        if ((threadIdx.x & 63) == 0 && m > 0.0f)
            atomicMax(maxbits, __float_as_uint(m));  // bit order == float order
    }

    // ---- part A: copy + mirror (fully coalesced) ----
    const int PLANE4 = NNODES * CC / 4;       // 40000 float4 per (b,t) plane
    const int total  = BB * T_IN * PLANE4;    // 1,920,000
    for (int i = g0; i < total; i += gs) {
        int bt = i / PLANE4;
        int qq = i - bt * PLANE4;
        int b  = bt / T_IN;
        int t  = bt - b * T_IN;
        float4 v = x[i];
        out[((size_t)(b * T_OUT + t)) * PLANE4 + qq] = v;
        uint2 pk;
        pk.x = bf16rne(v.x) | (bf16rne(v.y) << 16);
        pk.y = bf16rne(v.z) | (bf16rne(v.w) << 16);
        xbu[i] = pk;
    }
}

// --- vbuild4: per-node wj (in LDS) + combined V -> global Vb2 -------------
__launch_bounds__(192)
__global__ void vbuild4_kernel(const int* __restrict__ nn,
                               const float* __restrict__ nd,
                               const float* __restrict__ Wsh,
                               const unsigned* __restrict__ maxbits,
                               unsigned* __restrict__ Vb2) {
    __shared__ float wjl[144];   // wj[j(18)][h(8)], j=17 pad
    const int n = blockIdx.x, tid = threadIdx.x;
    if (tid < 144) {
        int j = tid >> 3, h = tid & 7;
        float wv = 0.f;
        if (j < K1) {
            float mx = __uint_as_float(*maxbits);
            float inv_s2 = 4.0f / (mx * mx);      // 1/sigma^2, sigma = mx/2
            float dv = nd[n * K1 + j];
            float lam = (float)(h + 1) * 0.125f;
            wv = expf(-dv * dv * lam * inv_s2);
            if (nn[n * K1 + j] == -1 || wv < 1e-5f) wv = 0.0f;
        }
        wjl[tid] = wv;
    }
    __syncthreads();
    if (tid < 144) {
        const int t = tid / 12;
        const int o = tid - t * 12;
        float Wcol[8];
#pragma unroll
        for (int h = 0; h < 8; ++h) Wcol[h] = Wsh[(t * 8 + h) * 12 + o];
        unsigned* vn = Vb2 + (size_t)n * VND + (t / 3) * VQD + (t % 3) * 12 + o;
#pragma unroll
        for (int jp = 0; jp < JP; ++jp) {
            float4 a0 = *(const float4*)&wjl[jp * 16];       // wj[2jp][0..3]
            float4 a1 = *(const float4*)&wjl[jp * 16 + 4];
            float4 b0 = *(const float4*)&wjl[jp * 16 + 8];   // wj[2jp+1]
            float4 b1 = *(const float4*)&wjl[jp * 16 + 12];
            float wa[8] = {a0.x, a0.y, a0.z, a0.w, a1.x, a1.y, a1.z, a1.w};
            float wb[8] = {b0.x, b0.y, b0.z, b0.w, b1.x, b1.y, b1.z, b1.w};
            float v0 = 0.f, v1 = 0.f;
#pragma unroll
            for (int h = 0; h < 8; ++h) {
                v0 = fmaf(wa[h], Wcol[h], v0);
                v1 = fmaf(wb[h], Wcol[h], v1);
            }
            vn[jp * VJPD] = bf16rne(v0) | (bf16rne(v1) << 16);
        }
    }
}

// --- main11: main5 structure (V 2-buf SGPR, 3-deep X, 2-stage reduce), ----
// ---          gathers from TPU-layout mirror [b][t][n][c2] ----------------
struct VBlk { uint4 v[9]; };

__device__ __forceinline__ unsigned u4c(const uint4& u, int i) {
    switch (i) { case 0: return u.x; case 1: return u.y;
                 case 2: return u.z; default: return u.w; }
}

#define DOT2(ACC, XP, VP) \
    asm("v_dot2_f32_bf16 %0, %1, %2, %0" : "+v"(ACC) : "v"(XP), "s"(VP))

__launch_bounds__(256)
__global__ void gnn_main11_kernel(const unsigned* __restrict__ xbu,
                                  const unsigned* __restrict__ Vb2,
                                  const int* __restrict__ nn,
                                  const float* __restrict__ bsh,
                                  float* __restrict__ out) {
    __shared__ float pb2[2][24][65];   // 12.48 KB (2-stage reduction)
    __shared__ float bl[O_OUT];

    const int n    = blockIdx.x;
    const int tid  = threadIdx.x;
    const int q    = __builtin_amdgcn_readfirstlane(tid >> 6);
    const int lane = tid & 63;
    const int bb   = lane >> 4;
    const int c2   = lane & 15;

    if (tid < O_OUT) bl[tid] = bsh[tid];

    int nnv[18];
#pragma unroll
    for (int j = 0; j < K1; ++j) nnv[j] = max(nn[n * K1 + j], 0);
    nnv[17] = nnv[16];   // pad pair partner (V high half is 0 there)

    // TPU layout: xlane points at (b, t=3q) plane, channel-pair c2
    const unsigned* xlane = xbu + (bb * T_IN + 3 * q) * TPU + c2;
    const unsigned* vbase = Vb2 + (size_t)n * VND + q * VQD;

    float pf[24];
#pragma unroll
    for (int i = 0; i < 24; ++i) pf[i] = 0.f;

#define VLOADP(DST, JPI) do {                                                \
        const uint4* vp_ = (const uint4*)(vbase + (JPI) * VJPD);             \
        _Pragma("unroll")                                                    \
        for (int i_ = 0; i_ < 9; ++i_) DST.v[i_] = vp_[i_];                  \
    } while (0)

#define XLOADP(E0, E1, E2, O0, O1, O2, JPI) do {                             \
        const unsigned* xe_ = xlane + nnv[2 * (JPI)] * 16;                   \
        const unsigned* xo_ = xlane + nnv[2 * (JPI) + 1] * 16;               \
        E0 = xe_[0]; E1 = xe_[TPU]; E2 = xe_[2 * TPU];                       \
        O0 = xo_[0]; O1 = xo_[TPU]; O2 = xo_[2 * TPU];                       \
    } while (0)

#define COMPP(VV, E0, E1, E2, O0, O1, O2) do {                               \
        unsigned xe_[3] = {E0, E1, E2};                                      \
        unsigned xo_[3] = {O0, O1, O2};                                      \
        _Pragma("unroll")                                                    \
        for (int t_ = 0; t_ < 3; ++t_) {                                     \
            unsigned plo_ = __builtin_amdgcn_perm(xe_[t_], xo_[t_],          \
                                                  0x01000504u);              \
            unsigned phi_ = __builtin_amdgcn_perm(xe_[t_], xo_[t_],          \
                                                  0x03020706u);              \
            _Pragma("unroll")                                                \
            for (int o_ = 0; o_ < 12; ++o_) {                                \
                unsigned vp_ = u4c(VV.v[t_ * 3 + (o_ >> 2)], o_ & 3);        \
                DOT2(pf[o_],      plo_, vp_);                                \
                DOT2(pf[12 + o_], phi_, vp_);                                \
            }                                                                \
        }                                                                    \
    } while (0)

    VBlk va, vb;
    unsigned e00, e01, e02, o00, o01, o02;   // X buf 0
    unsigned e10, e11, e12, o10, o11, o12;   // X buf 1
    unsigned e20, e21, e22, o20, o21, o22;   // X buf 2

    // prologue: X 2-deep, V 2-deep
    XLOADP(e00, e01, e02, o00, o01, o02, 0);
    XLOADP(e10, e11, e12, o10, o11, o12, 1);
    VLOADP(va, 0);
    VLOADP(vb, 1);
    // jp=0
    XLOADP(e20, e21, e22, o20, o21, o22, 2);
    COMPP(va, e00, e01, e02, o00, o01, o02);
    VLOADP(va, 2);
    // jp=1
    XLOADP(e00, e01, e02, o00, o01, o02, 3);
    COMPP(vb, e10, e11, e12, o10, o11, o12);
    VLOADP(vb, 3);
    // jp=2
    XLOADP(e10, e11, e12, o10, o11, o12, 4);
    COMPP(va, e20, e21, e22, o20, o21, o22);
    VLOADP(va, 4);
    // jp=3
    XLOADP(e20, e21, e22, o20, o21, o22, 5);
    COMPP(vb, e00, e01, e02, o00, o01, o02);
    VLOADP(vb, 5);
    // jp=4
    XLOADP(e00, e01, e02, o00, o01, o02, 6);
    COMPP(va, e10, e11, e12, o10, o11, o12);
    VLOADP(va, 6);
    // jp=5
    XLOADP(e10, e11, e12, o10, o11, o12, 7);
    COMPP(vb, e20, e21, e22, o20, o21, o22);
    VLOADP(vb, 7);
    // jp=6
    XLOADP(e20, e21, e22, o20, o21, o22, 8);
    COMPP(va, e00, e01, e02, o00, o01, o02);
    VLOADP(va, 8);
    // jp=7
    COMPP(vb, e10, e11, e12, o10, o11, o12);
    // jp=8
    COMPP(va, e20, e21, e22, o20, o21, o22);

#undef VLOADP
#undef XLOADP
#undef COMPP

    // --- 2-stage cross-wave (q) reduction, bias + swish + store ---
    if (q >= 2) {
#pragma unroll
        for (int i = 0; i < 24; ++i) pb2[q - 2][i][lane] = pf[i];
    }
    __syncthreads();
    if (q < 2) {
#pragma unroll
        for (int i = 0; i < 24; ++i) pf[i] += pb2[q][i][lane];
    }
    if (q == 1) {
#pragma unroll
        for (int i = 0; i < 24; ++i) pb2[1][i][lane] = pf[i];
    }
    __syncthreads();
    if (q == 0) {
        float* ob = out + ((size_t)(bb * T_OUT + T_IN) * NNODES + n) * CC + 2 * c2;
#pragma unroll
        for (int o = 0; o < O_OUT; ++o) {
            float v0 = pf[o]      + pb2[1][o][lane]      + bl[o];
            float v1 = pf[12 + o] + pb2[1][12 + o][lane] + bl[o];
            float s0 = v0 / (1.f + expf(-0.8f * v0));
            float s1 = v1 / (1.f + expf(-0.8f * v1));
            *(float2*)(ob + (size_t)o * XSTRIDE) = make_float2(s0, s1);
        }
    }
}

// ======================= fallback path (round-3) ==========================
template <int PACK>
__global__ void prep_kernel(const float4* __restrict__ x,
                            float4* __restrict__ out,
                            uint2* __restrict__ xb) {
    const int PLANE4 = NNODES * CC / 4;
    const int total  = BB * T_IN * PLANE4;
    for (int i = blockIdx.x * blockDim.x + threadIdx.x; i < total;
         i += gridDim.x * blockDim.x) {
        int bt = i / PLANE4;
        int qq = i - bt * PLANE4;
        int b  = bt / T_IN;
        int t  = bt - b * T_IN;
        float4 v = x[i];
        out[((size_t)(b * T_OUT + t)) * PLANE4 + qq] = v;
        if (PACK) {
            uint2 pk;
            pk.x = bf16rne(v.x) | (bf16rne(v.y) << 16);
            pk.y = bf16rne(v.z) | (bf16rne(v.w) << 16);
            xb[i] = pk;
        }
    }
}

template <int USEBF>
__launch_bounds__(256)
__global__ void gnn_main_kernel(const float* __restrict__ x,
                                const unsigned* __restrict__ xbu,
                                const int* __restrict__ nn,
                                const float* __restrict__ nd,
                                const float* __restrict__ Wsh,
                                const float* __restrict__ bsh,
                                const unsigned* __restrict__ maxbits,
                                float* __restrict__ out) {
    __shared__ float wl[K1][HH];
    __shared__ float Wl[96][O_OUT];
    __shared__ float bl_s[O_OUT];
    __shared__ int   nnl[K1];

    const int n   = blockIdx.x;
    const int tid = threadIdx.x;
    const int rg  = tid >> 4;
    const int c2  = tid & 15;
    const int b   = rg >> 2;
    const int q   = rg & 3;

    for (int i = tid; i < 288; i += 256)
        ((float4*)Wl)[i] = ((const float4*)Wsh)[i];
    if (tid < O_OUT) bl_s[tid] = bsh[tid];
    if (tid < K1 * HH) {
        int j = tid >> 3, h = tid & 7;
        int v = nn[n * K1 + j];
        float dv = nd[n * K1 + j];
        float mx = __uint_as_float(*maxbits);
        float inv_s2 = 4.0f / (mx * mx);
        float lam = (float)(h + 1) * 0.125f;
        float wv = expf(-dv * dv * lam * inv_s2);
        if (v == -1 || wv < 1e-5f) wv = 0.0f;
        wl[j][h] = wv;
    }
    if (tid < K1) nnl[tid] = max(nn[n * K1 + tid], 0);
    __syncthreads();

    float acc[3][2][8];
#pragma unroll
    for (int k = 0; k < 3; ++k)
#pragma unroll
        for (int cc = 0; cc < 2; ++cc)
#pragma unroll
            for (int h = 0; h < 8; ++h) acc[k][cc][h] = 0.f;

    if (USEBF) {
        const unsigned* xbase = xbu + (b * T_IN + 3 * q) * TPU + c2;
        unsigned ua0, ua1, ua2, ub0, ub1, ub2;
#define LOADB(u0, u1, u2, J) do {                                            \
        int idx_ = __builtin_amdgcn_readfirstlane(nnl[(J)]);                 \
        const unsigned* bp_ = xbase + idx_ * 16;                             \
        u0 = bp_[0]; u1 = bp_[TPU]; u2 = bp_[2 * TPU];                       \
    } while (0)
#define COMPB(u0, u1, u2, J) do {                                            \
        float4 wA_ = *(const float4*)&wl[(J)][0];                            \
        float4 wB_ = *(const float4*)&wl[(J)][4];                            \
        float wv_[8] = {wA_.x, wA_.y, wA_.z, wA_.w,                          \
                        wB_.x, wB_.y, wB_.z, wB_.w};                         \
        float xl_[3] = {__uint_as_float(u0 << 16),                           \
                        __uint_as_float(u1 << 16),                           \
                        __uint_as_float(u2 << 16)};                          \
        float xh_[3] = {__uint_as_float(u0 & 0xffff0000u),                   \
                        __uint_as_float(u1 & 0xffff0000u),                   \
                        __uint_as_float(u2 & 0xffff0000u)};                  \
        _Pragma("unroll")                                                    \
        for (int k_ = 0; k_ < 3; ++k_)                                       \
            _Pragma("unroll")                                                \
            for (int h_ = 0; h_ < 8; ++h_) {                                 \
                acc[k_][0][h_] = fmaf(wv_[h_], xl_[k_], acc[k_][0][h_]);     \
                acc[k_][1][h_] = fmaf(wv_[h_], xh_[k_], acc[k_][1][h_]);     \
            }                                                                \
    } while (0)
        LOADB(ua0, ua1, ua2, 0);
#pragma unroll 1
        for (int jj = 0; jj < 8; ++jj) {
            LOADB(ub0, ub1, ub2, 2 * jj + 1);
            COMPB(ua0, ua1, ua2, 2 * jj);
            LOADB(ua0, ua1, ua2, 2 * jj + 2);
            COMPB(ub0, ub1, ub2, 2 * jj + 1);
        }
        COMPB(ua0, ua1, ua2, 16);
#undef LOADB
#undef COMPB
    } else {
        const float* xbase = x + (b * T_IN + 3 * q) * XSTRIDE + 2 * c2;
        float2 xa0, xa1, xa2, xb0, xb1, xb2;
#define LOADJ(v0, v1, v2, J) do {                                            \
        int idx_ = __builtin_amdgcn_readfirstlane(nnl[(J)]);                 \
        const float* bp_ = xbase + idx_ * CC;                                \
        v0 = *(const float2*)(bp_);                                          \
        v1 = *(const float2*)(bp_ + XSTRIDE);                                \
        v2 = *(const float2*)(bp_ + 2 * XSTRIDE);                            \
    } while (0)
#define COMPJ(v0, v1, v2, J) do {                                            \
        float4 wA_ = *(const float4*)&wl[(J)][0];                            \
        float4 wB_ = *(const float4*)&wl[(J)][4];                            \
        float wv_[8] = {wA_.x, wA_.y, wA_.z, wA_.w,                          \
                        wB_.x, wB_.y, wB_.z, wB_.w};                         \
        float xv_[3][2] = {{v0.x, v0.y}, {v1.x, v1.y}, {v2.x, v2.y}};        \
        _Pragma("unroll")                                                    \
        for (int k_ = 0; k_ < 3; ++k_)                                       \
            _Pragma("unroll")                                                \
            for (int cc_ = 0; cc_ < 2; ++cc_)                                \
                _Pragma("unroll")                                            \
                for (int h_ = 0; h_ < 8; ++h_)                               \
                    acc[k_][cc_][h_] =                                       \
                        fmaf(wv_[h_], xv_[k_][cc_], acc[k_][cc_][h_]);       \
    } while (0)
        LOADJ(xa0, xa1, xa2, 0);
#pragma unroll 1
        for (int jj = 0; jj < 8; ++jj) {
            LOADJ(xb0, xb1, xb2, 2 * jj + 1);
            COMPJ(xa0, xa1, xa2, 2 * jj);
            LOADJ(xa0, xa1, xa2, 2 * jj + 2);
            COMPJ(xb0, xb1, xb2, 2 * jj + 1);
        }
        COMPJ(xa0, xa1, xa2, 16);
#undef LOADJ
#undef COMPJ
    }

    float p[2][O_OUT];
#pragma unroll
    for (int o = 0; o < O_OUT; ++o) { p[0][o] = 0.f; p[1][o] = 0.f; }
#pragma unroll
    for (int k = 0; k < 3; ++k) {
#pragma unroll
        for (int h = 0; h < 8; ++h) {
            int row = (3 * q + k) * 8 + h;
            const float4* wr = (const float4*)&Wl[row][0];
            float4 w0 = wr[0], w1 = wr[1], w2 = wr[2];
            float wrow[12] = {w0.x, w0.y, w0.z, w0.w,
                              w1.x, w1.y, w1.z, w1.w,
                              w2.x, w2.y, w2.z, w2.w};
            float a0 = acc[k][0][h], a1 = acc[k][1][h];
#pragma unroll
            for (int o = 0; o < O_OUT; ++o) {
                p[0][o] = fmaf(a0, wrow[o], p[0][o]);
                p[1][o] = fmaf(a1, wrow[o], p[1][o]);
            }
        }
    }
#pragma unroll
    for (int cc = 0; cc < 2; ++cc)
#pragma unroll
        for (int o = 0; o < O_OUT; ++o) {
            float v = p[cc][o];
            v += __shfl_xor(v, 16, 64);
            v += __shfl_xor(v, 32, 64);
            p[cc][o] = v;
        }
    if (q == 0) {
        float* ob = out + ((size_t)(b * T_OUT + T_IN) * NNODES + n) * CC + 2 * c2;
#pragma unroll
        for (int o = 0; o < O_OUT; ++o) {
            float v0 = p[0][o] + bl_s[o];
            float v1 = p[1][o] + bl_s[o];
            float s0 = v0 / (1.f + expf(-0.8f * v0));
            float s1 = v1 / (1.f + expf(-0.8f * v1));
            *(float2*)(ob + (size_t)o * XSTRIDE) = make_float2(s0, s1);
        }
    }
}

extern "C" void kernel_launch(void* const* d_in, const int* in_sizes, int n_in,
                              void* d_out, int out_size, void* d_ws, size_t ws_size,
                              hipStream_t stream) {
    const float* x   = (const float*)d_in[0];
    const int*   nn  = (const int*)d_in[1];
    const float* nd  = (const float*)d_in[2];
    const float* Wsh = (const float*)d_in[3];
    const float* bsh = (const float*)d_in[4];
    float* out = (float*)d_out;

    unsigned* maxbits = (unsigned*)d_ws;
    hipMemsetAsync(d_ws, 0, sizeof(unsigned), stream);

    const size_t xbu_off = 1024;
    const size_t xbu_sz  = (size_t)BB * T_IN * NNODES * CC * 2;   // 15,360,000
    const size_t vb_off  = xbu_off + xbu_sz;                      // 16B aligned
    const size_t vb_sz   = (size_t)NNODES * VND * 4;              // 25,920,000
    const size_t need2   = vb_off + vb_sz;                        // ~41.3 MB

    if (ws_size >= need2) {
        uint2*    xbu = (uint2*)((char*)d_ws + xbu_off);
        unsigned* Vb2 = (unsigned*)((char*)d_ws + vb_off);

        prep5b_kernel<<<2048, 256, 0, stream>>>(
            (const float4*)x, (float4*)out, xbu, nd, maxbits);
        vbuild4_kernel<<<NNODES, 192, 0, stream>>>(nn, nd, Wsh, maxbits, Vb2);
        gnn_main11_kernel<<<NNODES, 256, 0, stream>>>(
            (const unsigned*)xbu, Vb2, nn, bsh, out);
    } else {
        max_reduce_kernel<<<128, 256, 0, stream>>>(nd, NNODES * K1, maxbits);
        unsigned* xbu = (unsigned*)((char*)d_ws + 256);
        const size_t need1 = 256 + (size_t)BB * T_IN * NNODES * CC * 2;
        if (ws_size >= need1) {
            prep_kernel<1><<<2048, 256, 0, stream>>>((const float4*)x,
                                                     (float4*)out, (uint2*)xbu);
            gnn_main_kernel<1><<<NNODES, 256, 0, stream>>>(x, xbu, nn, nd, Wsh,
                                                           bsh, maxbits, out);
        } else {
            prep_kernel<0><<<2048, 256, 0, stream>>>((const float4*)x,
                                                     (float4*)out, (uint2*)xbu);
            gnn_main_kernel<0><<<NNODES, 256, 0, stream>>>(x, xbu, nn, nd, Wsh,
                                                           bsh, maxbits, out);
        }
    }
}

// Round 14
// 100.459 us; speedup vs baseline: 1.1458x; 1.1458x over previous
//
#include <hip/hip_runtime.h>

#define BB     4
#define T_IN   12
#define T_OUT  24
#define NNODES 5000
#define CC     32
#define HH     8
#define K1     17
#define O_OUT  12
#define XSTRIDE (NNODES*CC)   // floats per (b,t) plane
#define TPU     (NNODES*16)   // legacy mirror plane (fallback path)

// bf16 x-mirror: xb2[b][node][t][c2] dwords (dword = bf16 ch-pair 2c2,2c2+1)
#define XB2_BN  192               // dwords per (b,node) = 12 t * 16 c2
#define XB2_B   (NNODES*XB2_BN)   // dwords per b
// V j-pair-packed: Vb2[n][q(4)][jp(9)][tq(3)][o(12)] dwords;
// dword = (bf16 V[2jp,t,o] low, bf16 V[2jp+1,t,o] high); jp=8 high half = 0.
#define JP      9
#define VJPD    36                // dwords per (q,jp) block = 3*12
#define VQD     (JP*VJPD)         // 324 dwords per (n,q)
#define VND     (4*VQD)           // 1296 dwords per node

// ---------------- kernel: global max (fallback path only) ----------------
__global__ void max_reduce_kernel(const float* __restrict__ d, int n,
                                  unsigned* __restrict__ out) {
    float m = 0.0f;
    for (int i = blockIdx.x * blockDim.x + threadIdx.x; i < n;
         i += gridDim.x * blockDim.x)
        m = fmaxf(m, d[i]);
#pragma unroll
    for (int off = 32; off > 0; off >>= 1)
        m = fmaxf(m, __shfl_down(m, off, 64));
    if ((threadIdx.x & 63) == 0)
        atomicMax(out, __float_as_uint(m));
}

__device__ inline unsigned bf16rne(float f) {
    unsigned u = __float_as_uint(f);
    return (u + 0x7FFFu + ((u >> 16) & 1u)) >> 16;
}

// ------ prep5: fused max-reduce + copy x->out[:, :T_IN] + xb2 mirror ------
__global__ void prep5_kernel(const float4* __restrict__ x,
                             float4* __restrict__ out,
                             uint4* __restrict__ xb2,
                             const float* __restrict__ nd,
                             unsigned* __restrict__ maxbits) {
    const int gs = gridDim.x * blockDim.x;
    const int g0 = blockIdx.x * blockDim.x + threadIdx.x;

    // ---- part 0: global max over nearest_dists (vbuild4 reads it later) ----
    {
        float m = 0.0f;  // dists >= 0
        for (int i = g0; i < NNODES * K1; i += gs) m = fmaxf(m, nd[i]);
#pragma unroll
        for (int off = 32; off > 0; off >>= 1)
            m = fmaxf(m, __shfl_down(m, off, 64));
        if ((threadIdx.x & 63) == 0 && m > 0.0f)
            atomicMax(maxbits, __float_as_uint(m));  // bit order == float order
    }

    // ---- part A: copy + xb2 mirror ----
    const int totalA = BB * T_IN * NNODES;   // 240000 (b,t,n) rows
    for (int i = g0; i < totalA; i += gs) {
        int bt = i / NNODES;
        int nd_ = i - bt * NNODES;
        int b  = bt / T_IN;
        int t  = bt - b * T_IN;
        const float4* xr = x + (size_t)i * 8;
        float4* orow = out + ((size_t)(b * T_OUT + t) * NNODES + nd_) * 8;
        uint4* xrow  = xb2 + ((size_t)(b * NNODES + nd_) * T_IN + t) * 4;
#pragma unroll
        for (int vq = 0; vq < 4; ++vq) {
            float4 v0 = xr[2 * vq], v1 = xr[2 * vq + 1];
            orow[2 * vq] = v0; orow[2 * vq + 1] = v1;
            uint4 pk;
            pk.x = bf16rne(v0.x) | (bf16rne(v0.y) << 16);
            pk.y = bf16rne(v0.z) | (bf16rne(v0.w) << 16);
            pk.z = bf16rne(v1.x) | (bf16rne(v1.y) << 16);
            pk.w = bf16rne(v1.z) | (bf16rne(v1.w) << 16);
            xrow[vq] = pk;
        }
    }
}

// --- vbuild4: per-node wj (in LDS) + combined V -> global Vb2 -------------
__launch_bounds__(192)
__global__ void vbuild4_kernel(const int* __restrict__ nn,
                               const float* __restrict__ nd,
                               const float* __restrict__ Wsh,
                               const unsigned* __restrict__ maxbits,
                               unsigned* __restrict__ Vb2) {
    __shared__ float wjl[144];   // wj[j(18)][h(8)], j=17 pad
    const int n = blockIdx.x, tid = threadIdx.x;
    if (tid < 144) {
        int j = tid >> 3, h = tid & 7;
        float wv = 0.f;
        if (j < K1) {
            float mx = __uint_as_float(*maxbits);
            float inv_s2 = 4.0f / (mx * mx);      // 1/sigma^2, sigma = mx/2
            float dv = nd[n * K1 + j];
            float lam = (float)(h + 1) * 0.125f;
            wv = expf(-dv * dv * lam * inv_s2);
            if (nn[n * K1 + j] == -1 || wv < 1e-5f) wv = 0.0f;
        }
        wjl[tid] = wv;
    }
    __syncthreads();
    if (tid < 144) {
        const int t = tid / 12;
        const int o = tid - t * 12;
        float Wcol[8];
#pragma unroll
        for (int h = 0; h < 8; ++h) Wcol[h] = Wsh[(t * 8 + h) * 12 + o];
        unsigned* vn = Vb2 + (size_t)n * VND + (t / 3) * VQD + (t % 3) * 12 + o;
#pragma unroll
        for (int jp = 0; jp < JP; ++jp) {
            float4 a0 = *(const float4*)&wjl[jp * 16];       // wj[2jp][0..3]
            float4 a1 = *(const float4*)&wjl[jp * 16 + 4];
            float4 b0 = *(const float4*)&wjl[jp * 16 + 8];   // wj[2jp+1]
            float4 b1 = *(const float4*)&wjl[jp * 16 + 12];
            float wa[8] = {a0.x, a0.y, a0.z, a0.w, a1.x, a1.y, a1.z, a1.w};
            float wb[8] = {b0.x, b0.y, b0.z, b0.w, b1.x, b1.y, b1.z, b1.w};
            float v0 = 0.f, v1 = 0.f;
#pragma unroll
            for (int h = 0; h < 8; ++h) {
                v0 = fmaf(wa[h], Wcol[h], v0);
                v1 = fmaf(wb[h], Wcol[h], v1);
            }
            vn[jp * VJPD] = bf16rne(v0) | (bf16rne(v1) << 16);
        }
    }
}

// --- main12: WAVE-PER-NODE — main5's SMEM-V pipeline ×4 q, zero LDS -------
struct VBlk { uint4 v[9]; };

__device__ __forceinline__ unsigned u4c(const uint4& u, int i) {
    switch (i) { case 0: return u.x; case 1: return u.y;
                 case 2: return u.z; default: return u.w; }
}

#define DOT2(ACC, XP, VP) \
    asm("v_dot2_f32_bf16 %0, %1, %2, %0" : "+v"(ACC) : "v"(XP), "s"(VP))

__launch_bounds__(256)
__global__ void gnn_main12_kernel(const unsigned* __restrict__ xb2,
                                  const unsigned* __restrict__ Vb2,
                                  const int* __restrict__ nn,
                                  const float* __restrict__ bsh,
                                  float* __restrict__ out) {
    const int tid  = threadIdx.x;
    const int w    = __builtin_amdgcn_readfirstlane(tid >> 6);  // wave id
    const int n    = blockIdx.x * 4 + w;                        // node (scalar)
    const int lane = tid & 63;
    const int bb   = lane >> 4;
    const int c2   = lane & 15;

    int nnv[18];
#pragma unroll
    for (int j = 0; j < K1; ++j) nnv[j] = max(nn[n * K1 + j], 0);  // s_load
    nnv[17] = nnv[16];   // pad pair partner (V high half is 0 there)

    const unsigned* xlane = xb2 + bb * XB2_B + c2;     // + idx*192 + t*16
    const unsigned* vnode = Vb2 + (size_t)n * VND;

    float pf[24];
#pragma unroll
    for (int i = 0; i < 24; ++i) pf[i] = 0.f;

#define VLOADP(DST, VB, JPI) do {                                            \
        const uint4* vp_ = (const uint4*)((VB) + (JPI) * VJPD);              \
        _Pragma("unroll")                                                    \
        for (int i_ = 0; i_ < 9; ++i_) DST.v[i_] = vp_[i_];                  \
    } while (0)

#define XLOADP(E0, E1, E2, O0, O1, O2, XQ, JPI) do {                         \
        const unsigned* xe_ = (XQ) + nnv[2 * (JPI)] * XB2_BN;                \
        const unsigned* xo_ = (XQ) + nnv[2 * (JPI) + 1] * XB2_BN;            \
        E0 = xe_[0]; E1 = xe_[16]; E2 = xe_[32];                             \
        O0 = xo_[0]; O1 = xo_[16]; O2 = xo_[32];                             \
    } while (0)

#define COMPP(VV, E0, E1, E2, O0, O1, O2) do {                               \
        unsigned xe_[3] = {E0, E1, E2};                                      \
        unsigned xo_[3] = {O0, O1, O2};                                      \
        _Pragma("unroll")                                                    \
        for (int t_ = 0; t_ < 3; ++t_) {                                     \
            unsigned plo_ = __builtin_amdgcn_perm(xe_[t_], xo_[t_],          \
                                                  0x01000504u);              \
            unsigned phi_ = __builtin_amdgcn_perm(xe_[t_], xo_[t_],          \
                                                  0x03020706u);              \
            _Pragma("unroll")                                                \
            for (int o_ = 0; o_ < 12; ++o_) {                                \
                unsigned vp_ = u4c(VV.v[t_ * 3 + (o_ >> 2)], o_ & 3);        \
                DOT2(pf[o_],      plo_, vp_);                                \
                DOT2(pf[12 + o_], phi_, vp_);                                \
            }                                                                \
        }                                                                    \
    } while (0)

#pragma unroll 1
    for (int q = 0; q < 4; ++q) {
        const unsigned* vbase = vnode + q * VQD;
        const unsigned* xq    = xlane + 48 * q;   // t = 3q + tq -> (3q+tq)*16

        VBlk va, vb;
        unsigned e00, e01, e02, o00, o01, o02;   // X buf 0
        unsigned e10, e11, e12, o10, o11, o12;   // X buf 1
        unsigned e20, e21, e22, o20, o21, o22;   // X buf 2

        // prologue: X 2-deep, V 2-deep
        XLOADP(e00, e01, e02, o00, o01, o02, xq, 0);
        XLOADP(e10, e11, e12, o10, o11, o12, xq, 1);
        VLOADP(va, vbase, 0);
        VLOADP(vb, vbase, 1);
        // jp=0
        XLOADP(e20, e21, e22, o20, o21, o22, xq, 2);
        COMPP(va, e00, e01, e02, o00, o01, o02);
        VLOADP(va, vbase, 2);
        // jp=1
        XLOADP(e00, e01, e02, o00, o01, o02, xq, 3);
        COMPP(vb, e10, e11, e12, o10, o11, o12);
        VLOADP(vb, vbase, 3);
        // jp=2
        XLOADP(e10, e11, e12, o10, o11, o12, xq, 4);
        COMPP(va, e20, e21, e22, o20, o21, o22);
        VLOADP(va, vbase, 4);
        // jp=3
        XLOADP(e20, e21, e22, o20, o21, o22, xq, 5);
        COMPP(vb, e00, e01, e02, o00, o01, o02);
        VLOADP(vb, vbase, 5);
        // jp=4
        XLOADP(e00, e01, e02, o00, o01, o02, xq, 6);
        COMPP(va, e10, e11, e12, o10, o11, o12);
        VLOADP(va, vbase, 6);
        // jp=5
        XLOADP(e10, e11, e12, o10, o11, o12, xq, 7);
        COMPP(vb, e20, e21, e22, o20, o21, o22);
        VLOADP(vb, vbase, 7);
        // jp=6
        XLOADP(e20, e21, e22, o20, o21, o22, xq, 8);
        COMPP(va, e00, e01, e02, o00, o01, o02);
        VLOADP(va, vbase, 8);
        // jp=7
        COMPP(vb, e10, e11, e12, o10, o11, o12);
        // jp=8
        COMPP(va, e20, e21, e22, o20, o21, o22);
    }

#undef VLOADP
#undef XLOADP
#undef COMPP

    // --- epilogue: bias + swish + store (all lanes, no reduction) ---
    float* ob = out + ((size_t)(bb * T_OUT + T_IN) * NNODES + n) * CC + 2 * c2;
#pragma unroll
    for (int o = 0; o < O_OUT; ++o) {
        float bo = bsh[o];                       // uniform -> s_load
        float v0 = pf[o] + bo;
        float v1 = pf[12 + o] + bo;
        float s0 = v0 / (1.f + expf(-0.8f * v0));
        float s1 = v1 / (1.f + expf(-0.8f * v1));
        *(float2*)(ob + (size_t)o * XSTRIDE) = make_float2(s0, s1);
    }
}

// ======================= fallback path (round-3) ==========================
template <int PACK>
__global__ void prep_kernel(const float4* __restrict__ x,
                            float4* __restrict__ out,
                            uint2* __restrict__ xb) {
    const int PLANE4 = NNODES * CC / 4;
    const int total  = BB * T_IN * PLANE4;
    for (int i = blockIdx.x * blockDim.x + threadIdx.x; i < total;
         i += gridDim.x * blockDim.x) {
        int bt = i / PLANE4;
        int qq = i - bt * PLANE4;
        int b  = bt / T_IN;
        int t  = bt - b * T_IN;
        float4 v = x[i];
        out[((size_t)(b * T_OUT + t)) * PLANE4 + qq] = v;
        if (PACK) {
            uint2 pk;
            pk.x = bf16rne(v.x) | (bf16rne(v.y) << 16);
            pk.y = bf16rne(v.z) | (bf16rne(v.w) << 16);
            xb[i] = pk;
        }
    }
}

template <int USEBF>
__launch_bounds__(256)
__global__ void gnn_main_kernel(const float* __restrict__ x,
                                const unsigned* __restrict__ xbu,
                                const int* __restrict__ nn,
                                const float* __restrict__ nd,
                                const float* __restrict__ Wsh,
                                const float* __restrict__ bsh,
                                const unsigned* __restrict__ maxbits,
                                float* __restrict__ out) {
    __shared__ float wl[K1][HH];
    __shared__ float Wl[96][O_OUT];
    __shared__ float bl_s[O_OUT];
    __shared__ int   nnl[K1];

    const int n   = blockIdx.x;
    const int tid = threadIdx.x;
    const int rg  = tid >> 4;
    const int c2  = tid & 15;
    const int b   = rg >> 2;
    const int q   = rg & 3;

    for (int i = tid; i < 288; i += 256)
        ((float4*)Wl)[i] = ((const float4*)Wsh)[i];
    if (tid < O_OUT) bl_s[tid] = bsh[tid];
    if (tid < K1 * HH) {
        int j = tid >> 3, h = tid & 7;
        int v = nn[n * K1 + j];
        float dv = nd[n * K1 + j];
        float mx = __uint_as_float(*maxbits);
        float inv_s2 = 4.0f / (mx * mx);
        float lam = (float)(h + 1) * 0.125f;
        float wv = expf(-dv * dv * lam * inv_s2);
        if (v == -1 || wv < 1e-5f) wv = 0.0f;
        wl[j][h] = wv;
    }
    if (tid < K1) nnl[tid] = max(nn[n * K1 + tid], 0);
    __syncthreads();

    float acc[3][2][8];
#pragma unroll
    for (int k = 0; k < 3; ++k)
#pragma unroll
        for (int cc = 0; cc < 2; ++cc)
#pragma unroll
            for (int h = 0; h < 8; ++h) acc[k][cc][h] = 0.f;

    if (USEBF) {
        const unsigned* xbase = xbu + (b * T_IN + 3 * q) * TPU + c2;
        unsigned ua0, ua1, ua2, ub0, ub1, ub2;
#define LOADB(u0, u1, u2, J) do {                                            \
        int idx_ = __builtin_amdgcn_readfirstlane(nnl[(J)]);                 \
        const unsigned* bp_ = xbase + idx_ * 16;                             \
        u0 = bp_[0]; u1 = bp_[TPU]; u2 = bp_[2 * TPU];                       \
    } while (0)
#define COMPB(u0, u1, u2, J) do {                                            \
        float4 wA_ = *(const float4*)&wl[(J)][0];                            \
        float4 wB_ = *(const float4*)&wl[(J)][4];                            \
        float wv_[8] = {wA_.x, wA_.y, wA_.z, wA_.w,                          \
                        wB_.x, wB_.y, wB_.z, wB_.w};                         \
        float xl_[3] = {__uint_as_float(u0 << 16),                           \
                        __uint_as_float(u1 << 16),                           \
                        __uint_as_float(u2 << 16)};                          \
        float xh_[3] = {__uint_as_float(u0 & 0xffff0000u),                   \
                        __uint_as_float(u1 & 0xffff0000u),                   \
                        __uint_as_float(u2 & 0xffff0000u)};                  \
        _Pragma("unroll")                                                    \
        for (int k_ = 0; k_ < 3; ++k_)                                       \
            _Pragma("unroll")                                                \
            for (int h_ = 0; h_ < 8; ++h_) {                                 \
                acc[k_][0][h_] = fmaf(wv_[h_], xl_[k_], acc[k_][0][h_]);     \
                acc[k_][1][h_] = fmaf(wv_[h_], xh_[k_], acc[k_][1][h_]);     \
            }                                                                \
    } while (0)
        LOADB(ua0, ua1, ua2, 0);
#pragma unroll 1
        for (int jj = 0; jj < 8; ++jj) {
            LOADB(ub0, ub1, ub2, 2 * jj + 1);
            COMPB(ua0, ua1, ua2, 2 * jj);
            LOADB(ua0, ua1, ua2, 2 * jj + 2);
            COMPB(ub0, ub1, ub2, 2 * jj + 1);
        }
        COMPB(ua0, ua1, ua2, 16);
#undef LOADB
#undef COMPB
    } else {
        const float* xbase = x + (b * T_IN + 3 * q) * XSTRIDE + 2 * c2;
        float2 xa0, xa1, xa2, xb0, xb1, xb2;
#define LOADJ(v0, v1, v2, J) do {                                            \
        int idx_ = __builtin_amdgcn_readfirstlane(nnl[(J)]);                 \
        const float* bp_ = xbase + idx_ * CC;                                \
        v0 = *(const float2*)(bp_);                                          \
        v1 = *(const float2*)(bp_ + XSTRIDE);                                \
        v2 = *(const float2*)(bp_ + 2 * XSTRIDE);                            \
    } while (0)
#define COMPJ(v0, v1, v2, J) do {                                            \
        float4 wA_ = *(const float4*)&wl[(J)][0];                            \
        float4 wB_ = *(const float4*)&wl[(J)][4];                            \
        float wv_[8] = {wA_.x, wA_.y, wA_.z, wA_.w,                          \
                        wB_.x, wB_.y, wB_.z, wB_.w};                         \
        float xv_[3][2] = {{v0.x, v0.y}, {v1.x, v1.y}, {v2.x, v2.y}};        \
        _Pragma("unroll")                                                    \
        for (int k_ = 0; k_ < 3; ++k_)                                       \
            _Pragma("unroll")                                                \
            for (int cc_ = 0; cc_ < 2; ++cc_)                                \
                _Pragma("unroll")                                            \
                for (int h_ = 0; h_ < 8; ++h_)                               \
                    acc[k_][cc_][h_] =                                       \
                        fmaf(wv_[h_], xv_[k_][cc_], acc[k_][cc_][h_]);       \
    } while (0)
        LOADJ(xa0, xa1, xa2, 0);
#pragma unroll 1
        for (int jj = 0; jj < 8; ++jj) {
            LOADJ(xb0, xb1, xb2, 2 * jj + 1);
            COMPJ(xa0, xa1, xa2, 2 * jj);
            LOADJ(xa0, xa1, xa2, 2 * jj + 2);
            COMPJ(xb0, xb1, xb2, 2 * jj + 1);
        }
        COMPJ(xa0, xa1, xa2, 16);
#undef LOADJ
#undef COMPJ
    }

    float p[2][O_OUT];
#pragma unroll
    for (int o = 0; o < O_OUT; ++o) { p[0][o] = 0.f; p[1][o] = 0.f; }
#pragma unroll
    for (int k = 0; k < 3; ++k) {
#pragma unroll
        for (int h = 0; h < 8; ++h) {
            int row = (3 * q + k) * 8 + h;
            const float4* wr = (const float4*)&Wl[row][0];
            float4 w0 = wr[0], w1 = wr[1], w2 = wr[2];
            float wrow[12] = {w0.x, w0.y, w0.z, w0.w,
                              w1.x, w1.y, w1.z, w1.w,
                              w2.x, w2.y, w2.z, w2.w};
            float a0 = acc[k][0][h], a1 = acc[k][1][h];
#pragma unroll
            for (int o = 0; o < O_OUT; ++o) {
                p[0][o] = fmaf(a0, wrow[o], p[0][o]);
                p[1][o] = fmaf(a1, wrow[o], p[1][o]);
            }
        }
    }
#pragma unroll
    for (int cc = 0; cc < 2; ++cc)
#pragma unroll
        for (int o = 0; o < O_OUT; ++o) {
            float v = p[cc][o];
            v += __shfl_xor(v, 16, 64);
            v += __shfl_xor(v, 32, 64);
            p[cc][o] = v;
        }
    if (q == 0) {
        float* ob = out + ((size_t)(b * T_OUT + T_IN) * NNODES + n) * CC + 2 * c2;
#pragma unroll
        for (int o = 0; o < O_OUT; ++o) {
            float v0 = p[0][o] + bl_s[o];
            float v1 = p[1][o] + bl_s[o];
            float s0 = v0 / (1.f + expf(-0.8f * v0));
            float s1 = v1 / (1.f + expf(-0.8f * v1));
            *(float2*)(ob + (size_t)o * XSTRIDE) = make_float2(s0, s1);
        }
    }
}

extern "C" void kernel_launch(void* const* d_in, const int* in_sizes, int n_in,
                              void* d_out, int out_size, void* d_ws, size_t ws_size,
                              hipStream_t stream) {
    const float* x   = (const float*)d_in[0];
    const int*   nn  = (const int*)d_in[1];
    const float* nd  = (const float*)d_in[2];
    const float* Wsh = (const float*)d_in[3];
    const float* bsh = (const float*)d_in[4];
    float* out = (float*)d_out;

    unsigned* maxbits = (unsigned*)d_ws;
    hipMemsetAsync(d_ws, 0, sizeof(unsigned), stream);

    const size_t xb2_off = 1024;
    const size_t xb2_sz  = (size_t)BB * NNODES * T_IN * 16 * 4;   // 15,360,000
    const size_t vb_off  = xb2_off + xb2_sz;                      // 16B aligned
    const size_t vb_sz   = (size_t)NNODES * VND * 4;              // 25,920,000
    const size_t need2   = vb_off + vb_sz;                        // ~41.3 MB

    if (ws_size >= need2) {
        uint4*    xb2 = (uint4*)((char*)d_ws + xb2_off);
        unsigned* Vb2 = (unsigned*)((char*)d_ws + vb_off);

        prep5_kernel<<<2048, 256, 0, stream>>>(
            (const float4*)x, (float4*)out, xb2, nd, maxbits);
        vbuild4_kernel<<<NNODES, 192, 0, stream>>>(nn, nd, Wsh, maxbits, Vb2);
        gnn_main12_kernel<<<NNODES / 4, 256, 0, stream>>>(
            (const unsigned*)xb2, Vb2, nn, bsh, out);
    } else {
        max_reduce_kernel<<<128, 256, 0, stream>>>(nd, NNODES * K1, maxbits);
        unsigned* xbu = (unsigned*)((char*)d_ws + 256);
        const size_t need1 = 256 + (size_t)BB * T_IN * NNODES * CC * 2;
        if (ws_size >= need1) {
            prep_kernel<1><<<2048, 256, 0, stream>>>((const float4*)x,
                                                     (float4*)out, (uint2*)xbu);
            gnn_main_kernel<1><<<NNODES, 256, 0, stream>>>(x, xbu, nn, nd, Wsh,
                                                           bsh, maxbits, out);
        } else {
            prep_kernel<0><<<2048, 256, 0, stream>>>((const float4*)x,
                                                     (float4*)out, (uint2*)xbu);
            gnn_main_kernel<0><<<NNODES, 256, 0, stream>>>(x, xbu, nn, nd, Wsh,
                                                           bsh, maxbits, out);
        }
    }
}

// Round 15
// 78.449 us; speedup vs baseline: 1.4672x; 1.2806x over previous
//
#include <hip/hip_runtime.h>

#define BB     4
#define T_IN   12
#define T_OUT  24
#define NNODES 5000
#define CC     32
#define HH     8
#define K1     17
#define O_OUT  12
#define XSTRIDE (NNODES*CC)   // floats per (b,t) plane
#define TPU     (NNODES*16)   // legacy mirror plane (fallback path)

// bf16 x-mirror: xb2[b][node][t][c2] dwords (dword = bf16 ch-pair 2c2,2c2+1)
#define XB2_BN  192               // dwords per (b,node) = 12 t * 16 c2
#define XB2_B   (NNODES*XB2_BN)   // dwords per b
// V j-pair-packed (in LDS): [q(4)][jp(9)][t(3)][o(12)] dwords;
// dword = (bf16 V[2jp,t,o] low, bf16 V[2jp+1,t,o] high); jp=8 high half = 0.
#define JP      9
#define VJPD    36                // dwords per (q,jp) block = 3*12
#define VQD     (JP*VJPD)         // 324 dwords per q
#define VND     (4*VQD)           // 1296 dwords total
#define WJN     144               // wj floats per node: [j(18)][h(8)], j=17 pad

// ---------------- kernel: global max over nearest_dists ----------------
__global__ void max_reduce_kernel(const float* __restrict__ d, int n,
                                  unsigned* __restrict__ out) {
    float m = 0.0f;  // dists >= 0
    for (int i = blockIdx.x * blockDim.x + threadIdx.x; i < n;
         i += gridDim.x * blockDim.x)
        m = fmaxf(m, d[i]);
#pragma unroll
    for (int off = 32; off > 0; off >>= 1)
        m = fmaxf(m, __shfl_down(m, off, 64));
    if ((threadIdx.x & 63) == 0)
        atomicMax(out, __float_as_uint(m));
}

__device__ inline unsigned bf16rne(float f) {
    unsigned u = __float_as_uint(f);
    return (u + 0x7FFFu + ((u >> 16) & 1u)) >> 16;
}

// --- prep4c: COALESCED copy + mirror (thread-per-float4) + wj table -------
__global__ void prep4c_kernel(const float4* __restrict__ x,
                              float4* __restrict__ out,
                              unsigned* __restrict__ xb2d,   // dword view
                              const int* __restrict__ nn,
                              const float* __restrict__ nd,
                              const unsigned* __restrict__ maxbits,
                              float* __restrict__ wjg) {
    const int gs = gridDim.x * blockDim.x;
    const int g0 = blockIdx.x * blockDim.x + threadIdx.x;

    // ---- A: copy x -> out[:, :T_IN] + bf16 mirror, fully coalesced ----
    const int PLANE4 = NNODES * CC / 4;       // 40000 float4 per (b,t) plane
    const int totalA = BB * T_IN * PLANE4;    // 1,920,000
    for (int i = g0; i < totalA; i += gs) {
        int bt = i / PLANE4;
        int qq = i - bt * PLANE4;
        int b  = bt / T_IN;
        int t  = bt - b * T_IN;
        float4 v = x[i];
        out[((size_t)(b * T_OUT + t)) * PLANE4 + qq] = v;   // coalesced
        // mirror: float4 = channels 4cq..4cq+3 of node n -> c2 = 2cq, 2cq+1
        int n  = qq >> 3;
        int cq = qq & 7;
        uint2 pk;
        pk.x = bf16rne(v.x) | (bf16rne(v.y) << 16);
        pk.y = bf16rne(v.z) | (bf16rne(v.w) << 16);
        // dword offset ((b*NNODES+n)*T_IN+t)*16 + 2cq  (8B aligned)
        *(uint2*)&xb2d[(((size_t)(b * NNODES + n)) * T_IN + t) * 16 + 2 * cq] = pk;
    }

    // ---- B: wj table (GCN weights) ----
    float mx = __uint_as_float(*maxbits);
    float inv_s2 = 4.0f / (mx * mx);          // 1/sigma^2, sigma = mx/2
    const int totalB = NNODES * WJN;
    for (int i = g0; i < totalB; i += gs) {
        int n = i / WJN;
        int r = i - n * WJN;
        int j = r >> 3, h = r & 7;
        float wv = 0.f;
        if (j < K1) {
            float dv = nd[n * K1 + j];
            float lam = (float)(h + 1) * 0.125f;
            wv = expf(-dv * dv * lam * inv_s2);
            if (nn[n * K1 + j] == -1 || wv < 1e-5f) wv = 0.0f;
        }
        wjg[i] = wv;
    }
}

// ------- main7: dot2 j-pairs, V computed in-block to LDS, 2-stage reduce ---
struct VBlk { uint4 v[9]; };

__device__ __forceinline__ unsigned u4c(const uint4& u, int i) {
    switch (i) { case 0: return u.x; case 1: return u.y;
                 case 2: return u.z; default: return u.w; }
}

#define DOT2(ACC, XP, VP) \
    asm("v_dot2_f32_bf16 %0, %1, %2, %0" : "+v"(ACC) : "v"(XP), "v"(VP))

__launch_bounds__(256)
__global__ void gnn_main7_kernel(const unsigned* __restrict__ xb2,
                                 const float* __restrict__ wjg,
                                 const float* __restrict__ Wsh,
                                 const int* __restrict__ nn,
                                 const float* __restrict__ bsh,
                                 float* __restrict__ out) {
    __shared__ float pb2[2][24][65];   // 12.48 KB (2-stage reduction)
    __shared__ unsigned Vl[VND];       // 5.18 KB combined-weight table
    __shared__ float bl[O_OUT];

    const int n    = blockIdx.x;
    const int tid  = threadIdx.x;
    const int q    = __builtin_amdgcn_readfirstlane(tid >> 6);
    const int lane = tid & 63;
    const int bb   = lane >> 4;
    const int c2   = lane & 15;

    if (tid < O_OUT) bl[tid] = bsh[tid];

    int nnv[18];
#pragma unroll
    for (int j = 0; j < K1; ++j) nnv[j] = max(nn[n * K1 + j], 0);
    nnv[17] = nnv[16];   // pad pair partner (V high half is 0 there)

    const unsigned* xlane = xb2 + bb * XB2_B + 48 * q + c2;

#define XLOADP(E0, E1, E2, O0, O1, O2, JPI) do {                             \
        const unsigned* xe_ = xlane + nnv[2 * (JPI)] * XB2_BN;               \
        const unsigned* xo_ = xlane + nnv[2 * (JPI) + 1] * XB2_BN;           \
        E0 = xe_[0]; E1 = xe_[16]; E2 = xe_[32];                             \
        O0 = xo_[0]; O1 = xo_[16]; O2 = xo_[32];                             \
    } while (0)

    unsigned e00, e01, e02, o00, o01, o02;   // X buf 0
    unsigned e10, e11, e12, o10, o11, o12;   // X buf 1
    unsigned e20, e21, e22, o20, o21, o22;   // X buf 2

    // issue first gathers early (long-latency, overlap V-compute)
    XLOADP(e00, e01, e02, o00, o01, o02, 0);
    XLOADP(e10, e11, e12, o10, o11, o12, 1);

    // ---- V-compute phase: V[q'][jp][t'][o] from wj (s_load) and W ----
    {
        const int t = tid / 12;                 // 0..11 valid for tid<144
        const int o = tid - t * 12;
        float Wcol[8];
        if (tid < 144) {
#pragma unroll
            for (int h = 0; h < 8; ++h) Wcol[h] = Wsh[(t * 8 + h) * 12 + o];
        }
        const float* wp = wjg + n * WJN;        // wave-uniform base
        const int vi = (t / 3) * VQD + (t % 3) * 12 + o;
#pragma unroll
        for (int jp = 0; jp < JP; ++jp) {
            float wa[16];
#pragma unroll
            for (int h = 0; h < 16; ++h) wa[h] = wp[jp * 16 + h];  // s_load
            if (tid < 144) {
                float v0 = 0.f, v1 = 0.f;
#pragma unroll
                for (int h = 0; h < 8; ++h) {
                    v0 = fmaf(wa[h],     Wcol[h], v0);
                    v1 = fmaf(wa[8 + h], Wcol[h], v1);
                }
                Vl[vi + jp * VJPD] = bf16rne(v0) | (bf16rne(v1) << 16);
            }
        }
    }

    float pf[24];
#pragma unroll
    for (int i = 0; i < 24; ++i) pf[i] = 0.f;

    __syncthreads();   // Vl ready

#define VLOADP(DST, JPI) do {                                                \
        const uint4* vp_ = (const uint4*)&Vl[q * VQD + (JPI) * VJPD];        \
        _Pragma("unroll")                                                    \
        for (int i_ = 0; i_ < 9; ++i_) DST.v[i_] = vp_[i_];                  \
    } while (0)

#define COMPP(VV, E0, E1, E2, O0, O1, O2) do {                               \
        unsigned xe_[3] = {E0, E1, E2};                                      \
        unsigned xo_[3] = {O0, O1, O2};                                      \
        _Pragma("unroll")                                                    \
        for (int t_ = 0; t_ < 3; ++t_) {                                     \
            unsigned plo_ = __builtin_amdgcn_perm(xe_[t_], xo_[t_],          \
                                                  0x01000504u);              \
            unsigned phi_ = __builtin_amdgcn_perm(xe_[t_], xo_[t_],          \
                                                  0x03020706u);              \
            _Pragma("unroll")                                                \
            for (int o_ = 0; o_ < 12; ++o_) {                                \
                unsigned vp_ = u4c(VV.v[t_ * 3 + (o_ >> 2)], o_ & 3);        \
                DOT2(pf[o_],      plo_, vp_);                                \
                DOT2(pf[12 + o_], phi_, vp_);                                \
            }                                                                \
        }                                                                    \
    } while (0)

    VBlk va, vb;
    VLOADP(va, 0);
    VLOADP(vb, 1);
    // jp=0
    XLOADP(e20, e21, e22, o20, o21, o22, 2);
    COMPP(va, e00, e01, e02, o00, o01, o02);
    VLOADP(va, 2);
    // jp=1
    XLOADP(e00, e01, e02, o00, o01, o02, 3);
    COMPP(vb, e10, e11, e12, o10, o11, o12);
    VLOADP(vb, 3);
    // jp=2
    XLOADP(e10, e11, e12, o10, o11, o12, 4);
    COMPP(va, e20, e21, e22, o20, o21, o22);
    VLOADP(va, 4);
    // jp=3
    XLOADP(e20, e21, e22, o20, o21, o22, 5);
    COMPP(vb, e00, e01, e02, o00, o01, o02);
    VLOADP(vb, 5);
    // jp=4
    XLOADP(e00, e01, e02, o00, o01, o02, 6);
    COMPP(va, e10, e11, e12, o10, o11, o12);
    VLOADP(va, 6);
    // jp=5
    XLOADP(e10, e11, e12, o10, o11, o12, 7);
    COMPP(vb, e20, e21, e22, o20, o21, o22);
    VLOADP(vb, 7);
    // jp=6
    XLOADP(e20, e21, e22, o20, o21, o22, 8);
    COMPP(va, e00, e01, e02, o00, o01, o02);
    VLOADP(va, 8);
    // jp=7
    COMPP(vb, e10, e11, e12, o10, o11, o12);
    // jp=8
    COMPP(va, e20, e21, e22, o20, o21, o22);

#undef VLOADP
#undef XLOADP
#undef COMPP

    // --- 2-stage cross-wave (q) reduction, bias + swish + store ---
    if (q >= 2) {
#pragma unroll
        for (int i = 0; i < 24; ++i) pb2[q - 2][i][lane] = pf[i];
    }
    __syncthreads();
    if (q < 2) {
#pragma unroll
        for (int i = 0; i < 24; ++i) pf[i] += pb2[q][i][lane];
    }
    if (q == 1) {
#pragma unroll
        for (int i = 0; i < 24; ++i) pb2[1][i][lane] = pf[i];
    }
    __syncthreads();
    if (q == 0) {
        float* ob = out + ((size_t)(bb * T_OUT + T_IN) * NNODES + n) * CC + 2 * c2;
#pragma unroll
        for (int o = 0; o < O_OUT; ++o) {
            float v0 = pf[o]      + pb2[1][o][lane]      + bl[o];
            float v1 = pf[12 + o] + pb2[1][12 + o][lane] + bl[o];
            float s0 = v0 / (1.f + expf(-0.8f * v0));
            float s1 = v1 / (1.f + expf(-0.8f * v1));
            *(float2*)(ob + (size_t)o * XSTRIDE) = make_float2(s0, s1);
        }
    }
}

// ======================= fallback path (round-3) ==========================
template <int PACK>
__global__ void prep_kernel(const float4* __restrict__ x,
                            float4* __restrict__ out,
                            uint2* __restrict__ xb) {
    const int PLANE4 = NNODES * CC / 4;
    const int total  = BB * T_IN * PLANE4;
    for (int i = blockIdx.x * blockDim.x + threadIdx.x; i < total;
         i += gridDim.x * blockDim.x) {
        int bt = i / PLANE4;
        int qq = i - bt * PLANE4;
        int b  = bt / T_IN;
        int t  = bt - b * T_IN;
        float4 v = x[i];
        out[((size_t)(b * T_OUT + t)) * PLANE4 + qq] = v;
        if (PACK) {
            uint2 pk;
            pk.x = bf16rne(v.x) | (bf16rne(v.y) << 16);
            pk.y = bf16rne(v.z) | (bf16rne(v.w) << 16);
            xb[i] = pk;
        }
    }
}

template <int USEBF>
__launch_bounds__(256)
__global__ void gnn_main_kernel(const float* __restrict__ x,
                                const unsigned* __restrict__ xbu,
                                const int* __restrict__ nn,
                                const float* __restrict__ nd,
                                const float* __restrict__ Wsh,
                                const float* __restrict__ bsh,
                                const unsigned* __restrict__ maxbits,
                                float* __restrict__ out) {
    __shared__ float wl[K1][HH];
    __shared__ float Wl[96][O_OUT];
    __shared__ float bl_s[O_OUT];
    __shared__ int   nnl[K1];

    const int n   = blockIdx.x;
    const int tid = threadIdx.x;
    const int rg  = tid >> 4;
    const int c2  = tid & 15;
    const int b   = rg >> 2;
    const int q   = rg & 3;

    for (int i = tid; i < 288; i += 256)
        ((float4*)Wl)[i] = ((const float4*)Wsh)[i];
    if (tid < O_OUT) bl_s[tid] = bsh[tid];
    if (tid < K1 * HH) {
        int j = tid >> 3, h = tid & 7;
        int v = nn[n * K1 + j];
        float dv = nd[n * K1 + j];
        float mx = __uint_as_float(*maxbits);
        float inv_s2 = 4.0f / (mx * mx);
        float lam = (float)(h + 1) * 0.125f;
        float wv = expf(-dv * dv * lam * inv_s2);
        if (v == -1 || wv < 1e-5f) wv = 0.0f;
        wl[j][h] = wv;
    }
    if (tid < K1) nnl[tid] = max(nn[n * K1 + tid], 0);
    __syncthreads();

    float acc[3][2][8];
#pragma unroll
    for (int k = 0; k < 3; ++k)
#pragma unroll
        for (int cc = 0; cc < 2; ++cc)
#pragma unroll
            for (int h = 0; h < 8; ++h) acc[k][cc][h] = 0.f;

    if (USEBF) {
        const unsigned* xbase = xbu + (b * T_IN + 3 * q) * TPU + c2;
        unsigned ua0, ua1, ua2, ub0, ub1, ub2;
#define LOADB(u0, u1, u2, J) do {                                            \
        int idx_ = __builtin_amdgcn_readfirstlane(nnl[(J)]);                 \
        const unsigned* bp_ = xbase + idx_ * 16;                             \
        u0 = bp_[0]; u1 = bp_[TPU]; u2 = bp_[2 * TPU];                       \
    } while (0)
#define COMPB(u0, u1, u2, J) do {                                            \
        float4 wA_ = *(const float4*)&wl[(J)][0];                            \
        float4 wB_ = *(const float4*)&wl[(J)][4];                            \
        float wv_[8] = {wA_.x, wA_.y, wA_.z, wA_.w,                          \
                        wB_.x, wB_.y, wB_.z, wB_.w};                         \
        float xl_[3] = {__uint_as_float(u0 << 16),                           \
                        __uint_as_float(u1 << 16),                           \
                        __uint_as_float(u2 << 16)};                          \
        float xh_[3] = {__uint_as_float(u0 & 0xffff0000u),                   \
                        __uint_as_float(u1 & 0xffff0000u),                   \
                        __uint_as_float(u2 & 0xffff0000u)};                  \
        _Pragma("unroll")                                                    \
        for (int k_ = 0; k_ < 3; ++k_)                                       \
            _Pragma("unroll")                                                \
            for (int h_ = 0; h_ < 8; ++h_) {                                 \
                acc[k_][0][h_] = fmaf(wv_[h_], xl_[k_], acc[k_][0][h_]);     \
                acc[k_][1][h_] = fmaf(wv_[h_], xh_[k_], acc[k_][1][h_]);     \
            }                                                                \
    } while (0)
        LOADB(ua0, ua1, ua2, 0);
#pragma unroll 1
        for (int jj = 0; jj < 8; ++jj) {
            LOADB(ub0, ub1, ub2, 2 * jj + 1);
            COMPB(ua0, ua1, ua2, 2 * jj);
            LOADB(ua0, ua1, ua2, 2 * jj + 2);
            COMPB(ub0, ub1, ub2, 2 * jj + 1);
        }
        COMPB(ua0, ua1, ua2, 16);
#undef LOADB
#undef COMPB
    } else {
        const float* xbase = x + (b * T_IN + 3 * q) * XSTRIDE + 2 * c2;
        float2 xa0, xa1, xa2, xb0, xb1, xb2;
#define LOADJ(v0, v1, v2, J) do {                                            \
        int idx_ = __builtin_amdgcn_readfirstlane(nnl[(J)]);                 \
        const float* bp_ = xbase + idx_ * CC;                                \
        v0 = *(const float2*)(bp_);                                          \
        v1 = *(const float2*)(bp_ + XSTRIDE);                                \
        v2 = *(const float2*)(bp_ + 2 * XSTRIDE);                            \
    } while (0)
#define COMPJ(v0, v1, v2, J) do {                                            \
        float4 wA_ = *(const float4*)&wl[(J)][0];                            \
        float4 wB_ = *(const float4*)&wl[(J)][4];                            \
        float wv_[8] = {wA_.x, wA_.y, wA_.z, wA_.w,                          \
                        wB_.x, wB_.y, wB_.z, wB_.w};                         \
        float xv_[3][2] = {{v0.x, v0.y}, {v1.x, v1.y}, {v2.x, v2.y}};        \
        _Pragma("unroll")                                                    \
        for (int k_ = 0; k_ < 3; ++k_)                                       \
            _Pragma("unroll")                                                \
            for (int cc_ = 0; cc_ < 2; ++cc_)                                \
                _Pragma("unroll")                                            \
                for (int h_ = 0; h_ < 8; ++h_)                               \
                    acc[k_][cc_][h_] =                                       \
                        fmaf(wv_[h_], xv_[k_][cc_], acc[k_][cc_][h_]);       \
    } while (0)
        LOADJ(xa0, xa1, xa2, 0);
#pragma unroll 1
        for (int jj = 0; jj < 8; ++jj) {
            LOADJ(xb0, xb1, xb2, 2 * jj + 1);
            COMPJ(xa0, xa1, xa2, 2 * jj);
            LOADJ(xa0, xa1, xa2, 2 * jj + 2);
            COMPJ(xb0, xb1, xb2, 2 * jj + 1);
        }
        COMPJ(xa0, xa1, xa2, 16);
#undef LOADJ
#undef COMPJ
    }

    float p[2][O_OUT];
#pragma unroll
    for (int o = 0; o < O_OUT; ++o) { p[0][o] = 0.f; p[1][o] = 0.f; }
#pragma unroll
    for (int k = 0; k < 3; ++k) {
#pragma unroll
        for (int h = 0; h < 8; ++h) {
            int row = (3 * q + k) * 8 + h;
            const float4* wr = (const float4*)&Wl[row][0];
            float4 w0 = wr[0], w1 = wr[1], w2 = wr[2];
            float wrow[12] = {w0.x, w0.y, w0.z, w0.w,
                              w1.x, w1.y, w1.z, w1.w,
                              w2.x, w2.y, w2.z, w2.w};
            float a0 = acc[k][0][h], a1 = acc[k][1][h];
#pragma unroll
            for (int o = 0; o < O_OUT; ++o) {
                p[0][o] = fmaf(a0, wrow[o], p[0][o]);
                p[1][o] = fmaf(a1, wrow[o], p[1][o]);
            }
        }
    }
#pragma unroll
    for (int cc = 0; cc < 2; ++cc)
#pragma unroll
        for (int o = 0; o < O_OUT; ++o) {
            float v = p[cc][o];
            v += __shfl_xor(v, 16, 64);
            v += __shfl_xor(v, 32, 64);
            p[cc][o] = v;
        }
    if (q == 0) {
        float* ob = out + ((size_t)(b * T_OUT + T_IN) * NNODES + n) * CC + 2 * c2;
#pragma unroll
        for (int o = 0; o < O_OUT; ++o) {
            float v0 = p[0][o] + bl_s[o];
            float v1 = p[1][o] + bl_s[o];
            float s0 = v0 / (1.f + expf(-0.8f * v0));
            float s1 = v1 / (1.f + expf(-0.8f * v1));
            *(float2*)(ob + (size_t)o * XSTRIDE) = make_float2(s0, s1);
        }
    }
}

extern "C" void kernel_launch(void* const* d_in, const int* in_sizes, int n_in,
                              void* d_out, int out_size, void* d_ws, size_t ws_size,
                              hipStream_t stream) {
    const float* x   = (const float*)d_in[0];
    const int*   nn  = (const int*)d_in[1];
    const float* nd  = (const float*)d_in[2];
    const float* Wsh = (const float*)d_in[3];
    const float* bsh = (const float*)d_in[4];
    float* out = (float*)d_out;

    unsigned* maxbits = (unsigned*)d_ws;
    hipMemsetAsync(d_ws, 0, sizeof(unsigned), stream);
    max_reduce_kernel<<<128, 256, 0, stream>>>(nd, NNODES * K1, maxbits);

    const size_t wjg_off = 1024;
    const size_t wjg_sz  = (size_t)NNODES * WJN * 4;              // 2,880,000
    const size_t xb2_off = wjg_off + wjg_sz;                      // 16B aligned
    const size_t xb2_sz  = (size_t)BB * NNODES * T_IN * 16 * 4;   // 15,360,000
    const size_t need2   = xb2_off + xb2_sz;                      // ~18.2 MB

    if (ws_size >= need2) {
        float*    wjg  = (float*)((char*)d_ws + wjg_off);
        unsigned* xb2d = (unsigned*)((char*)d_ws + xb2_off);

        prep4c_kernel<<<2048, 256, 0, stream>>>(
            (const float4*)x, (float4*)out, xb2d, nn, nd, maxbits, wjg);
        gnn_main7_kernel<<<NNODES, 256, 0, stream>>>(
            xb2d, wjg, Wsh, nn, bsh, out);
    } else {
        unsigned* xbu = (unsigned*)((char*)d_ws + 256);
        const size_t need1 = 256 + (size_t)BB * T_IN * NNODES * CC * 2;
        if (ws_size >= need1) {
            prep_kernel<1><<<2048, 256, 0, stream>>>((const float4*)x,
                                                     (float4*)out, (uint2*)xbu);
            gnn_main_kernel<1><<<NNODES, 256, 0, stream>>>(x, xbu, nn, nd, Wsh,
                                                           bsh, maxbits, out);
        } else {
            prep_kernel<0><<<2048, 256, 0, stream>>>((const float4*)x,
                                                     (float4*)out, (uint2*)xbu);
            gnn_main_kernel<0><<<NNODES, 256, 0, stream>>>(x, xbu, nn, nd, Wsh,
                                                           bsh, maxbits, out);
        }
    }
}